// Round 2
// baseline (470.603 us; speedup 1.0000x reference)
//
#include <hip/hip_runtime.h>
#include <hip/hip_bf16.h>

typedef __attribute__((ext_vector_type(8))) short short8;
typedef __attribute__((ext_vector_type(4))) short short4v;
typedef __attribute__((ext_vector_type(4))) float f32x4;

static inline size_t ws_align(size_t x) { return (x + 511) & ~((size_t)511); }

static __device__ inline unsigned short f2bf(float f) {
    __hip_bfloat16 h = __float2bfloat16(f);
    return __builtin_bit_cast(unsigned short, h);
}

// ---------------- dtype sniffing ----------------
// flags[0] = 1 if float inputs are fp32 (else bf16)
// flags[1] = 1 if edge_index is int64 (else int32)
__global__ void sniff_kernel(const unsigned short* __restrict__ w1,
                             const unsigned int* __restrict__ ei,
                             int* __restrict__ flags) {
    if (threadIdx.x == 0 && blockIdx.x == 0) {
        int c = 0, c2 = 0;
        for (int i = 0; i < 64; i++) {
            // even shorts: real bf16 values if bf16 data; fp32 low-mantissa garbage if fp32 data
            unsigned e = (w1[2 * i] >> 7) & 0xFF;
            if (e >= 100 && e <= 130) c++;
            // odd int32 slots: all zero iff int64 (values < 2^31)
            if (ei[2 * i + 1] == 0u) c2++;
        }
        flags[0] = (c < 48) ? 1 : 0;
        flags[1] = (c2 >= 48) ? 1 : 0;
    }
}

// ---------------- CSR build ----------------

__global__ void hist_kernel(const int* __restrict__ ei, const int* __restrict__ flags,
                            int* __restrict__ counts, int E) {
    int e = blockIdx.x * blockDim.x + threadIdx.x;
    if (e < E) {
        int d = flags[1] ? ei[2 * (size_t)E + 2 * e] : ei[(size_t)E + e];
        atomicAdd(&counts[d], 1);
    }
}

__global__ void dinv_kernel(const int* __restrict__ counts, float* __restrict__ dinv, int N) {
    int n = blockIdx.x * blockDim.x + threadIdx.x;
    if (n < N) {
        int d = counts[n];
        if (d < 1) d = 1;
        dinv[n] = rsqrtf((float)d);
    }
}

// single-block exclusive scan over N counts -> rowptr
__global__ __launch_bounds__(1024) void scan_kernel(const int* __restrict__ counts,
                                                    int* __restrict__ rowptr, int N) {
    __shared__ int lds[1024];
    const int t = threadIdx.x;
    const int C = (N + 1023) >> 10;
    const int base = t * C;
    int s = 0;
    for (int i = 0; i < C; i++) {
        int idx = base + i;
        if (idx < N) s += counts[idx];
    }
    lds[t] = s;
    __syncthreads();
    for (int off = 1; off < 1024; off <<= 1) {
        int v = (t >= off) ? lds[t - off] : 0;
        __syncthreads();
        lds[t] += v;
        __syncthreads();
    }
    int run = (t == 0) ? 0 : lds[t - 1];
    for (int i = 0; i < C; i++) {
        int idx = base + i;
        if (idx < N) {
            rowptr[idx] = run;
            run += counts[idx];
        }
    }
}

__global__ void fill_kernel(const int* __restrict__ ei, const int* __restrict__ flags,
                            const float* __restrict__ dinv, const int* __restrict__ rowptr,
                            int* __restrict__ woff, int2* __restrict__ edgedat, int E) {
    int e = blockIdx.x * blockDim.x + threadIdx.x;
    if (e < E) {
        int s, d;
        if (flags[1]) {
            s = ei[2 * e];
            d = ei[2 * (size_t)E + 2 * e];
        } else {
            s = ei[e];
            d = ei[(size_t)E + e];
        }
        int pos = rowptr[d] + atomicAdd(&woff[d], 1);
        float wt = dinv[s] * dinv[d];
        edgedat[pos] = make_int2(s, __float_as_int(wt));
    }
}

// ---------------- GEMM: out[N x FOUT] = A[N x 128] @ W[128 x FOUT], bf16 MFMA, bf16 out ----------------
// A may be bf16 or fp32 (a_follows && flags[0]); W follows flags[0].

template <int FOUT>
__global__ __launch_bounds__(256) void gemm_kernel(const void* __restrict__ Araw, int a_follows,
                                                   const void* __restrict__ Wraw,
                                                   const int* __restrict__ flags,
                                                   unsigned short* __restrict__ out, int Nrows) {
    constexpr int K = 128;
    constexpr int NT = FOUT / 16;
    constexpr int LDB = K + 8;
    __shared__ __align__(16) unsigned short bt[FOUT * LDB];  // bt[n][k] = W[k][n]

    const int tid = threadIdx.x;
    const int in_fp32 = flags[0];
    const int a_fp32 = a_follows & in_fp32;

    constexpr int TOT4 = K * FOUT / 4;
    if (in_fp32) {
        const float* Wf = (const float*)Wraw;
        for (int i = tid; i < TOT4; i += 256) {
            int idx = i * 4;
            int k = idx / FOUT;
            int n = idx & (FOUT - 1);
            float4 v = *(const float4*)(const void*)(Wf + idx);
            bt[(n + 0) * LDB + k] = f2bf(v.x);
            bt[(n + 1) * LDB + k] = f2bf(v.y);
            bt[(n + 2) * LDB + k] = f2bf(v.z);
            bt[(n + 3) * LDB + k] = f2bf(v.w);
        }
    } else {
        const unsigned short* Ws = (const unsigned short*)Wraw;
        for (int i = tid; i < TOT4; i += 256) {
            int idx = i * 4;
            int k = idx / FOUT;
            int n = idx & (FOUT - 1);
            short4v v = *(const short4v*)(const void*)(Ws + idx);
#pragma unroll
            for (int j = 0; j < 4; j++) bt[(n + j) * LDB + k] = ((const unsigned short*)&v)[j];
        }
    }

    const int wave = tid >> 6;
    const int lane = tid & 63;
    const int quad = lane >> 4;
    const int r16 = lane & 15;
    const int rowbase = blockIdx.x * 64 + wave * 16;

    int arow = rowbase + r16;
    if (arow > Nrows - 1) arow = Nrows - 1;

    short8 afrag[4];
    if (a_fp32) {
        const float* Ap = (const float*)Araw + (size_t)arow * K + quad * 8;
#pragma unroll
        for (int kk = 0; kk < 4; kk++) {
            float4 f0 = *(const float4*)(const void*)(Ap + kk * 32);
            float4 f1 = *(const float4*)(const void*)(Ap + kk * 32 + 4);
            short8 r;
            r[0] = (short)f2bf(f0.x); r[1] = (short)f2bf(f0.y);
            r[2] = (short)f2bf(f0.z); r[3] = (short)f2bf(f0.w);
            r[4] = (short)f2bf(f1.x); r[5] = (short)f2bf(f1.y);
            r[6] = (short)f2bf(f1.z); r[7] = (short)f2bf(f1.w);
            afrag[kk] = r;
        }
    } else {
        const unsigned short* Ap = (const unsigned short*)Araw + (size_t)arow * K + quad * 8;
#pragma unroll
        for (int kk = 0; kk < 4; kk++) afrag[kk] = *(const short8*)(const void*)(Ap + kk * 32);
    }

    __syncthreads();

    f32x4 acc[NT];
#pragma unroll
    for (int nt = 0; nt < NT; nt++) acc[nt] = (f32x4){0.f, 0.f, 0.f, 0.f};

#pragma unroll
    for (int kk = 0; kk < 4; kk++) {
#pragma unroll
        for (int nt = 0; nt < NT; nt++) {
            short8 b = *(const short8*)(const void*)(&bt[(nt * 16 + r16) * LDB + kk * 32 + quad * 8]);
            acc[nt] = __builtin_amdgcn_mfma_f32_16x16x32_bf16(afrag[kk], b, acc[nt], 0, 0, 0);
        }
    }

    // C layout: col = lane&15, row = quad*4 + r. Pack col pairs via shfl_xor; even lanes store bf16x2.
#pragma unroll
    for (int nt = 0; nt < NT; nt++) {
#pragma unroll
        for (int r = 0; r < 4; r++) {
            float v = acc[nt][r];
            float o = __shfl_xor(v, 1, 64);
            int row = rowbase + quad * 4 + r;
            if (((lane & 1) == 0) && row < Nrows) {
                __hip_bfloat162 pk;
                pk.x = __float2bfloat16(v);
                pk.y = __float2bfloat16(o);
                *(__hip_bfloat162*)(out + (size_t)row * FOUT + nt * 16 + r16) = pk;
            }
        }
    }
}

// ---------------- SpMM: Hout[n] = relu( sum_e w_e * Hin[src_e] ), wave per node ----------------

__global__ __launch_bounds__(256) void spmm128_kernel(const int2* __restrict__ edgedat,
                                                      const int* __restrict__ rowptr,
                                                      const int* __restrict__ counts,
                                                      const __hip_bfloat162* __restrict__ Hin,
                                                      __hip_bfloat162* __restrict__ Hout, int N) {
    int wid = (blockIdx.x * 256 + threadIdx.x) >> 6;
    if (wid >= N) return;
    int lane = threadIdx.x & 63;
    int n = __builtin_amdgcn_readfirstlane(wid);
    int start = rowptr[n];
    int len = counts[n];
    float ax = 0.f, ay = 0.f;
    for (int j = 0; j < len; j++) {
        int2 ed = edgedat[start + j];
        float wt = __int_as_float(ed.y);
        __hip_bfloat162 hv = Hin[(size_t)ed.x * 64 + lane];
        ax += wt * __bfloat162float(hv.x);
        ay += wt * __bfloat162float(hv.y);
    }
    __hip_bfloat162 pk;
    pk.x = __float2bfloat16(fmaxf(ax, 0.f));
    pk.y = __float2bfloat16(fmaxf(ay, 0.f));
    Hout[(size_t)n * 64 + lane] = pk;
}

__global__ __launch_bounds__(256) void spmm64_softmax_kernel(const int2* __restrict__ edgedat,
                                                             const int* __restrict__ rowptr,
                                                             const int* __restrict__ counts,
                                                             const __hip_bfloat16* __restrict__ Hin,
                                                             const int* __restrict__ flags,
                                                             void* __restrict__ Out, int N) {
    int wid = (blockIdx.x * 256 + threadIdx.x) >> 6;
    if (wid >= N) return;
    int lane = threadIdx.x & 63;
    int n = __builtin_amdgcn_readfirstlane(wid);
    int start = rowptr[n];
    int len = counts[n];
    float a = 0.f;
    for (int j = 0; j < len; j++) {
        int2 ed = edgedat[start + j];
        float wt = __int_as_float(ed.y);
        a += wt * __bfloat162float(Hin[(size_t)ed.x * 64 + lane]);
    }
    a = fmaxf(a, 0.f);   // relu
    float m = a;
#pragma unroll
    for (int off = 32; off > 0; off >>= 1) m = fmaxf(m, __shfl_xor(m, off, 64));
    float e = __expf(a - m);
    float s = e;
#pragma unroll
    for (int off = 32; off > 0; off >>= 1) s += __shfl_xor(s, off, 64);
    float r = e / s;
    if (flags[0]) {
        ((float*)Out)[(size_t)n * 64 + lane] = r;
    } else {
        ((unsigned short*)Out)[(size_t)n * 64 + lane] = f2bf(r);
    }
}

// ---------------- launch ----------------

extern "C" void kernel_launch(void* const* d_in, const int* in_sizes, int n_in,
                              void* d_out, int out_size, void* d_ws, size_t ws_size,
                              hipStream_t stream) {
    const void* X  = d_in[0];                       // [N,128] bf16 or fp32
    const int*  ei = (const int*)d_in[1];           // [2,E] int32 or int64
    const void* W1 = d_in[2];                       // [128,128]
    const void* W2 = d_in[3];                       // [128,128]
    const void* W3 = d_in[4];                       // [128,64]

    const int N = in_sizes[0] / 128;   // 50000
    const int E = in_sizes[1] / 2;     // 800000

    char* ws = (char*)d_ws;
    size_t off = 0;
    int* counts = (int*)(ws + off);   off += ws_align((size_t)N * 4);
    int* woff   = (int*)(ws + off);   off += ws_align((size_t)N * 4);
    const size_t zero_bytes = off;    // counts + woff need zeroing
    int* flags    = (int*)(ws + off);   off += ws_align(64);
    int* rowptr   = (int*)(ws + off);   off += ws_align((size_t)N * 4);
    float* dinv   = (float*)(ws + off); off += ws_align((size_t)N * 4);
    int2* edgedat = (int2*)(ws + off);  off += ws_align((size_t)E * 8);
    unsigned short* HA = (unsigned short*)(ws + off); off += ws_align((size_t)N * 128 * 2);
    unsigned short* HB = (unsigned short*)(ws + off); off += ws_align((size_t)N * 128 * 2);

    hipMemsetAsync(d_ws, 0, zero_bytes, stream);

    sniff_kernel<<<1, 64, 0, stream>>>((const unsigned short*)W1, (const unsigned int*)ei, flags);
    hist_kernel<<<(E + 255) / 256, 256, 0, stream>>>(ei, flags, counts, E);
    dinv_kernel<<<(N + 255) / 256, 256, 0, stream>>>(counts, dinv, N);
    scan_kernel<<<1, 1024, 0, stream>>>(counts, rowptr, N);
    fill_kernel<<<(E + 255) / 256, 256, 0, stream>>>(ei, flags, dinv, rowptr, woff, edgedat, E);

    const int gblocks = (N + 63) / 64;
    const int sblocks = (N * 64 + 255) / 256;

    // layer 1: HA = X @ W1 ; HB = relu(A_norm HA)
    gemm_kernel<128><<<gblocks, 256, 0, stream>>>(X, 1, W1, flags, HA, N);
    spmm128_kernel<<<sblocks, 256, 0, stream>>>(edgedat, rowptr, counts,
                                                (const __hip_bfloat162*)HA, (__hip_bfloat162*)HB, N);
    // layer 2
    gemm_kernel<128><<<gblocks, 256, 0, stream>>>(HB, 0, W2, flags, HA, N);
    spmm128_kernel<<<sblocks, 256, 0, stream>>>(edgedat, rowptr, counts,
                                                (const __hip_bfloat162*)HA, (__hip_bfloat162*)HB, N);
    // layer 3 (F_out = 64) + relu + softmax
    gemm_kernel<64><<<gblocks, 256, 0, stream>>>(HB, 0, W3, flags, HA, N);
    spmm64_softmax_kernel<<<sblocks, 256, 0, stream>>>(edgedat, rowptr, counts,
                                                       (const __hip_bfloat16*)HA, flags, d_out, N);
}

// Round 3
// 302.226 us; speedup vs baseline: 1.5571x; 1.5571x over previous
//
#include <hip/hip_runtime.h>
#include <hip/hip_bf16.h>

typedef __attribute__((ext_vector_type(8))) short short8;
typedef __attribute__((ext_vector_type(4))) short short4v;
typedef __attribute__((ext_vector_type(4))) float f32x4;

static inline size_t ws_align(size_t x) { return (x + 511) & ~((size_t)511); }

static __device__ inline unsigned short f2bf(float f) {
    __hip_bfloat16 h = __float2bfloat16(f);
    return __builtin_bit_cast(unsigned short, h);
}

// ---------------- dtype sniffing (64 lanes + ballot) ----------------
// flags[0] = 1 if float inputs are fp32 (else bf16)
// flags[1] = 1 if edge_index is int64 (else int32)
__global__ void sniff_kernel(const unsigned short* __restrict__ w1,
                             const unsigned int* __restrict__ ei,
                             int* __restrict__ flags) {
    int i = threadIdx.x;  // 64 threads
    unsigned e = (w1[2 * i] >> 7) & 0xFF;
    unsigned long long m1 = __ballot(e >= 100 && e <= 130);
    unsigned long long m2 = __ballot(ei[2 * i + 1] == 0u);
    if (i == 0) {
        flags[0] = (__popcll(m1) < 48) ? 1 : 0;
        flags[1] = (__popcll(m2) >= 48) ? 1 : 0;
    }
}

// ---------------- CSR build ----------------

__global__ void hist_kernel(const int* __restrict__ ei, const int* __restrict__ flags,
                            int* __restrict__ counts, int E) {
    int e = blockIdx.x * blockDim.x + threadIdx.x;
    if (e < E) {
        int d = flags[1] ? ei[2 * (size_t)E + 2 * e] : ei[(size_t)E + e];
        atomicAdd(&counts[d], 1);
    }
}

// fused: dinv + segment allocation (wave-scan + one atomic per wave).
// rowptr order across waves is arbitrary — spmm only needs per-node contiguity.
__global__ __launch_bounds__(256) void alloc_kernel(const int* __restrict__ counts,
                                                    float* __restrict__ dinv,
                                                    int* __restrict__ rowptr,
                                                    int* __restrict__ total, int N) {
    int n = blockIdx.x * blockDim.x + threadIdx.x;
    int lane = threadIdx.x & 63;
    int c = (n < N) ? counts[n] : 0;
    if (n < N) {
        int d = (c < 1) ? 1 : c;
        dinv[n] = rsqrtf((float)d);
    }
    int incl = c;
#pragma unroll
    for (int off = 1; off < 64; off <<= 1) {
        int v = __shfl_up(incl, off, 64);
        if (lane >= off) incl += v;
    }
    int wavetot = __shfl(incl, 63, 64);
    int base = 0;
    if (lane == 0) base = atomicAdd(total, wavetot);
    base = __shfl(base, 0, 64);
    if (n < N) rowptr[n] = base + incl - c;
}

__global__ void fill_kernel(const int* __restrict__ ei, const int* __restrict__ flags,
                            const float* __restrict__ dinv, const int* __restrict__ rowptr,
                            int* __restrict__ woff, int2* __restrict__ edgedat, int E) {
    int e = blockIdx.x * blockDim.x + threadIdx.x;
    if (e < E) {
        int s, d;
        if (flags[1]) {
            s = ei[2 * e];
            d = ei[2 * (size_t)E + 2 * e];
        } else {
            s = ei[e];
            d = ei[(size_t)E + e];
        }
        int pos = rowptr[d] + atomicAdd(&woff[d], 1);
        float wt = dinv[s] * dinv[d];
        edgedat[pos] = make_int2(s, __float_as_int(wt));
    }
}

// ---------------- GEMM: out[N x FOUT] = A[N x 128] @ W[128 x FOUT], bf16 MFMA ----------------
// 256 threads = 4 waves; each wave computes 2 row-tiles of 16 -> 128 rows/block.

template <int FOUT>
__global__ __launch_bounds__(256) void gemm_kernel(const void* __restrict__ Araw, int a_follows,
                                                   const void* __restrict__ Wraw,
                                                   const int* __restrict__ flags,
                                                   unsigned short* __restrict__ out, int Nrows) {
    constexpr int K = 128;
    constexpr int NT = FOUT / 16;
    constexpr int LDB = K + 8;
    __shared__ __align__(16) unsigned short bt[FOUT * LDB];  // bt[n][k] = W[k][n]

    const int tid = threadIdx.x;
    const int in_fp32 = flags[0];
    const int a_fp32 = a_follows & in_fp32;

    constexpr int TOT4 = K * FOUT / 4;
    if (in_fp32) {
        const float* Wf = (const float*)Wraw;
        for (int i = tid; i < TOT4; i += 256) {
            int idx = i * 4;
            int k = idx / FOUT;
            int n = idx & (FOUT - 1);
            float4 v = *(const float4*)(const void*)(Wf + idx);
            bt[(n + 0) * LDB + k] = f2bf(v.x);
            bt[(n + 1) * LDB + k] = f2bf(v.y);
            bt[(n + 2) * LDB + k] = f2bf(v.z);
            bt[(n + 3) * LDB + k] = f2bf(v.w);
        }
    } else {
        const unsigned short* Ws = (const unsigned short*)Wraw;
        for (int i = tid; i < TOT4; i += 256) {
            int idx = i * 4;
            int k = idx / FOUT;
            int n = idx & (FOUT - 1);
            short4v v = *(const short4v*)(const void*)(Ws + idx);
#pragma unroll
            for (int j = 0; j < 4; j++) bt[(n + j) * LDB + k] = ((const unsigned short*)&v)[j];
        }
    }

    const int wave = tid >> 6;
    const int lane = tid & 63;
    const int quad = lane >> 4;
    const int r16 = lane & 15;

    short8 afrag[2][4];
#pragma unroll
    for (int t = 0; t < 2; t++) {
        int arow = blockIdx.x * 128 + t * 64 + wave * 16 + r16;
        if (arow > Nrows - 1) arow = Nrows - 1;
        if (a_fp32) {
            const float* Ap = (const float*)Araw + (size_t)arow * K + quad * 8;
#pragma unroll
            for (int kk = 0; kk < 4; kk++) {
                float4 f0 = *(const float4*)(const void*)(Ap + kk * 32);
                float4 f1 = *(const float4*)(const void*)(Ap + kk * 32 + 4);
                short8 r;
                r[0] = (short)f2bf(f0.x); r[1] = (short)f2bf(f0.y);
                r[2] = (short)f2bf(f0.z); r[3] = (short)f2bf(f0.w);
                r[4] = (short)f2bf(f1.x); r[5] = (short)f2bf(f1.y);
                r[6] = (short)f2bf(f1.z); r[7] = (short)f2bf(f1.w);
                afrag[t][kk] = r;
            }
        } else {
            const unsigned short* Ap = (const unsigned short*)Araw + (size_t)arow * K + quad * 8;
#pragma unroll
            for (int kk = 0; kk < 4; kk++) afrag[t][kk] = *(const short8*)(const void*)(Ap + kk * 32);
        }
    }

    __syncthreads();

    f32x4 acc[2][NT];
#pragma unroll
    for (int t = 0; t < 2; t++)
#pragma unroll
        for (int nt = 0; nt < NT; nt++) acc[t][nt] = (f32x4){0.f, 0.f, 0.f, 0.f};

#pragma unroll
    for (int kk = 0; kk < 4; kk++) {
#pragma unroll
        for (int nt = 0; nt < NT; nt++) {
            short8 b = *(const short8*)(const void*)(&bt[(nt * 16 + r16) * LDB + kk * 32 + quad * 8]);
#pragma unroll
            for (int t = 0; t < 2; t++)
                acc[t][nt] = __builtin_amdgcn_mfma_f32_16x16x32_bf16(afrag[t][kk], b, acc[t][nt], 0, 0, 0);
        }
    }

    // C layout: col = lane&15, row = quad*4 + r. Pack col pairs via shfl_xor; even lanes store bf16x2.
#pragma unroll
    for (int t = 0; t < 2; t++) {
#pragma unroll
        for (int nt = 0; nt < NT; nt++) {
#pragma unroll
            for (int r = 0; r < 4; r++) {
                float v = acc[t][nt][r];
                float o = __shfl_xor(v, 1, 64);
                int row = blockIdx.x * 128 + t * 64 + wave * 16 + quad * 4 + r;
                if (((lane & 1) == 0) && row < Nrows) {
                    __hip_bfloat162 pk;
                    pk.x = __float2bfloat16(v);
                    pk.y = __float2bfloat16(o);
                    *(__hip_bfloat162*)(out + (size_t)row * FOUT + nt * 16 + r16) = pk;
                }
            }
        }
    }
}

// ---------------- SpMM: wave per node, 4-edge unroll for MLP ----------------

__global__ __launch_bounds__(256) void spmm128_kernel(const int2* __restrict__ edgedat,
                                                      const int* __restrict__ rowptr,
                                                      const int* __restrict__ counts,
                                                      const __hip_bfloat162* __restrict__ Hin,
                                                      __hip_bfloat162* __restrict__ Hout, int N) {
    int wid = (blockIdx.x * 256 + threadIdx.x) >> 6;
    if (wid >= N) return;
    int lane = threadIdx.x & 63;
    int n = __builtin_amdgcn_readfirstlane(wid);
    int start = __builtin_amdgcn_readfirstlane(rowptr[n]);
    int len = __builtin_amdgcn_readfirstlane(counts[n]);
    float ax = 0.f, ay = 0.f;
    int j = 0;
    for (; j + 4 <= len; j += 4) {
        int2 e0 = edgedat[start + j + 0];
        int2 e1 = edgedat[start + j + 1];
        int2 e2 = edgedat[start + j + 2];
        int2 e3 = edgedat[start + j + 3];
        __hip_bfloat162 h0 = Hin[(size_t)e0.x * 64 + lane];
        __hip_bfloat162 h1 = Hin[(size_t)e1.x * 64 + lane];
        __hip_bfloat162 h2 = Hin[(size_t)e2.x * 64 + lane];
        __hip_bfloat162 h3 = Hin[(size_t)e3.x * 64 + lane];
        float w0 = __int_as_float(e0.y), w1 = __int_as_float(e1.y);
        float w2 = __int_as_float(e2.y), w3 = __int_as_float(e3.y);
        ax += w0 * __bfloat162float(h0.x); ay += w0 * __bfloat162float(h0.y);
        ax += w1 * __bfloat162float(h1.x); ay += w1 * __bfloat162float(h1.y);
        ax += w2 * __bfloat162float(h2.x); ay += w2 * __bfloat162float(h2.y);
        ax += w3 * __bfloat162float(h3.x); ay += w3 * __bfloat162float(h3.y);
    }
    for (; j < len; j++) {
        int2 ed = edgedat[start + j];
        float wt = __int_as_float(ed.y);
        __hip_bfloat162 hv = Hin[(size_t)ed.x * 64 + lane];
        ax += wt * __bfloat162float(hv.x);
        ay += wt * __bfloat162float(hv.y);
    }
    __hip_bfloat162 pk;
    pk.x = __float2bfloat16(fmaxf(ax, 0.f));
    pk.y = __float2bfloat16(fmaxf(ay, 0.f));
    Hout[(size_t)n * 64 + lane] = pk;
}

__global__ __launch_bounds__(256) void spmm64_softmax_kernel(const int2* __restrict__ edgedat,
                                                             const int* __restrict__ rowptr,
                                                             const int* __restrict__ counts,
                                                             const __hip_bfloat16* __restrict__ Hin,
                                                             const int* __restrict__ flags,
                                                             void* __restrict__ Out, int N) {
    int wid = (blockIdx.x * 256 + threadIdx.x) >> 6;
    if (wid >= N) return;
    int lane = threadIdx.x & 63;
    int n = __builtin_amdgcn_readfirstlane(wid);
    int start = __builtin_amdgcn_readfirstlane(rowptr[n]);
    int len = __builtin_amdgcn_readfirstlane(counts[n]);
    float a = 0.f;
    int j = 0;
    for (; j + 4 <= len; j += 4) {
        int2 e0 = edgedat[start + j + 0];
        int2 e1 = edgedat[start + j + 1];
        int2 e2 = edgedat[start + j + 2];
        int2 e3 = edgedat[start + j + 3];
        float h0 = __bfloat162float(Hin[(size_t)e0.x * 64 + lane]);
        float h1 = __bfloat162float(Hin[(size_t)e1.x * 64 + lane]);
        float h2 = __bfloat162float(Hin[(size_t)e2.x * 64 + lane]);
        float h3 = __bfloat162float(Hin[(size_t)e3.x * 64 + lane]);
        a += __int_as_float(e0.y) * h0;
        a += __int_as_float(e1.y) * h1;
        a += __int_as_float(e2.y) * h2;
        a += __int_as_float(e3.y) * h3;
    }
    for (; j < len; j++) {
        int2 ed = edgedat[start + j];
        a += __int_as_float(ed.y) * __bfloat162float(Hin[(size_t)ed.x * 64 + lane]);
    }
    a = fmaxf(a, 0.f);   // relu
    float m = a;
#pragma unroll
    for (int off = 32; off > 0; off >>= 1) m = fmaxf(m, __shfl_xor(m, off, 64));
    float e = __expf(a - m);
    float s = e;
#pragma unroll
    for (int off = 32; off > 0; off >>= 1) s += __shfl_xor(s, off, 64);
    float r = e / s;
    if (flags[0]) {
        ((float*)Out)[(size_t)n * 64 + lane] = r;
    } else {
        ((unsigned short*)Out)[(size_t)n * 64 + lane] = f2bf(r);
    }
}

// ---------------- launch ----------------

extern "C" void kernel_launch(void* const* d_in, const int* in_sizes, int n_in,
                              void* d_out, int out_size, void* d_ws, size_t ws_size,
                              hipStream_t stream) {
    const void* X  = d_in[0];                       // [N,128] bf16 or fp32
    const int*  ei = (const int*)d_in[1];           // [2,E] int32 or int64
    const void* W1 = d_in[2];                       // [128,128]
    const void* W2 = d_in[3];                       // [128,128]
    const void* W3 = d_in[4];                       // [128,64]

    const int N = in_sizes[0] / 128;   // 50000
    const int E = in_sizes[1] / 2;     // 800000

    char* ws = (char*)d_ws;
    size_t off = 0;
    int* counts = (int*)(ws + off);   off += ws_align((size_t)N * 4);
    int* woff   = (int*)(ws + off);   off += ws_align((size_t)N * 4);
    int* total  = (int*)(ws + off);   off += ws_align(64);
    const size_t zero_bytes = off;    // counts + woff + total need zeroing
    int* flags    = (int*)(ws + off);   off += ws_align(64);
    int* rowptr   = (int*)(ws + off);   off += ws_align((size_t)N * 4);
    float* dinv   = (float*)(ws + off); off += ws_align((size_t)N * 4);
    int2* edgedat = (int2*)(ws + off);  off += ws_align((size_t)E * 8);
    unsigned short* HA = (unsigned short*)(ws + off); off += ws_align((size_t)N * 128 * 2);
    unsigned short* HB = (unsigned short*)(ws + off); off += ws_align((size_t)N * 128 * 2);

    hipMemsetAsync(d_ws, 0, zero_bytes, stream);

    sniff_kernel<<<1, 64, 0, stream>>>((const unsigned short*)W1, (const unsigned int*)ei, flags);
    hist_kernel<<<(E + 255) / 256, 256, 0, stream>>>(ei, flags, counts, E);
    alloc_kernel<<<(N + 255) / 256, 256, 0, stream>>>(counts, dinv, rowptr, total, N);
    fill_kernel<<<(E + 255) / 256, 256, 0, stream>>>(ei, flags, dinv, rowptr, woff, edgedat, E);

    const int gblocks = (N + 127) / 128;
    const int sblocks = (N * 64 + 255) / 256;

    // layer 1: HA = X @ W1 ; HB = relu(A_norm HA)
    gemm_kernel<128><<<gblocks, 256, 0, stream>>>(X, 1, W1, flags, HA, N);
    spmm128_kernel<<<sblocks, 256, 0, stream>>>(edgedat, rowptr, counts,
                                                (const __hip_bfloat162*)HA, (__hip_bfloat162*)HB, N);
    // layer 2
    gemm_kernel<128><<<gblocks, 256, 0, stream>>>(HB, 0, W2, flags, HA, N);
    spmm128_kernel<<<sblocks, 256, 0, stream>>>(edgedat, rowptr, counts,
                                                (const __hip_bfloat162*)HA, (__hip_bfloat162*)HB, N);
    // layer 3 (F_out = 64) + relu + softmax
    gemm_kernel<64><<<gblocks, 256, 0, stream>>>(HB, 0, W3, flags, HA, N);
    spmm64_softmax_kernel<<<sblocks, 256, 0, stream>>>(edgedat, rowptr, counts,
                                                       (const __hip_bfloat16*)HA, flags, d_out, N);
}

// Round 4
// 271.523 us; speedup vs baseline: 1.7332x; 1.1131x over previous
//
#include <hip/hip_runtime.h>
#include <hip/hip_bf16.h>

typedef __attribute__((ext_vector_type(8))) short short8;
typedef __attribute__((ext_vector_type(4))) short short4v;
typedef __attribute__((ext_vector_type(4))) float f32x4;

static inline size_t ws_align(size_t x) { return (x + 511) & ~((size_t)511); }

static __device__ inline unsigned short f2bf(float f) {
    __hip_bfloat16 h = __float2bfloat16(f);
    return __builtin_bit_cast(unsigned short, h);
}

// ---------------- dtype sniffing (64 lanes + ballot) ----------------
// flags[0] = 1 if float inputs are fp32 (else bf16)
// flags[1] = 1 if edge_index is int64 (else int32)
__global__ void sniff_kernel(const unsigned short* __restrict__ w1,
                             const unsigned int* __restrict__ ei,
                             int* __restrict__ flags) {
    int i = threadIdx.x;  // 64 threads
    unsigned e = (w1[2 * i] >> 7) & 0xFF;
    unsigned long long m1 = __ballot(e >= 100 && e <= 130);
    unsigned long long m2 = __ballot(ei[2 * i + 1] == 0u);
    if (i == 0) {
        flags[0] = (__popcll(m1) < 48) ? 1 : 0;
        flags[1] = (__popcll(m2) >= 48) ? 1 : 0;
    }
}

// ---------------- CSR build ----------------
// hist: count + record stable local offset per edge (the atomic's return value).
__global__ void hist_kernel(const int* __restrict__ ei, const int* __restrict__ flags,
                            int* __restrict__ counts, int* __restrict__ loff, int E) {
    int e = blockIdx.x * blockDim.x + threadIdx.x;
    if (e < E) {
        int d = flags[1] ? ei[2 * (size_t)E + 2 * e] : ei[(size_t)E + e];
        loff[e] = atomicAdd(&counts[d], 1);
    }
}

// fused: dinv + segment allocation (wave-scan + one atomic per wave).
// rowptr order across waves is arbitrary — spmm only needs per-node contiguity.
__global__ __launch_bounds__(256) void alloc_kernel(const int* __restrict__ counts,
                                                    float* __restrict__ dinv,
                                                    int* __restrict__ rowptr,
                                                    int* __restrict__ total, int N) {
    int n = blockIdx.x * blockDim.x + threadIdx.x;
    int lane = threadIdx.x & 63;
    int c = (n < N) ? counts[n] : 0;
    if (n < N) {
        int d = (c < 1) ? 1 : c;
        dinv[n] = rsqrtf((float)d);
    }
    int incl = c;
#pragma unroll
    for (int off = 1; off < 64; off <<= 1) {
        int v = __shfl_up(incl, off, 64);
        if (lane >= off) incl += v;
    }
    int wavetot = __shfl(incl, 63, 64);
    int base = 0;
    if (lane == 0) base = atomicAdd(total, wavetot);
    base = __shfl(base, 0, 64);
    if (n < N) rowptr[n] = base + incl - c;
}

// atomic-free fill: position comes from rowptr + recorded local offset.
__global__ void fill_kernel(const int* __restrict__ ei, const int* __restrict__ flags,
                            const float* __restrict__ dinv, const int* __restrict__ rowptr,
                            const int* __restrict__ loff, int2* __restrict__ edgedat, int E) {
    int e = blockIdx.x * blockDim.x + threadIdx.x;
    if (e < E) {
        int s, d;
        if (flags[1]) {
            s = ei[2 * e];
            d = ei[2 * (size_t)E + 2 * e];
        } else {
            s = ei[e];
            d = ei[(size_t)E + e];
        }
        int pos = rowptr[d] + loff[e];
        float wt = dinv[s] * dinv[d];
        edgedat[pos] = make_int2(s, __float_as_int(wt));
    }
}

// ---------------- GEMM: out[N x FOUT] = A[N x 128] @ W[128 x FOUT], bf16 MFMA ----------------
// 256 threads = 4 waves; each wave computes 2 row-tiles of 16 -> 128 rows/block.

template <int FOUT>
__global__ __launch_bounds__(256) void gemm_kernel(const void* __restrict__ Araw, int a_follows,
                                                   const void* __restrict__ Wraw,
                                                   const int* __restrict__ flags,
                                                   unsigned short* __restrict__ out, int Nrows) {
    constexpr int K = 128;
    constexpr int NT = FOUT / 16;
    constexpr int LDB = K + 8;
    __shared__ __align__(16) unsigned short bt[FOUT * LDB];  // bt[n][k] = W[k][n]

    const int tid = threadIdx.x;
    const int in_fp32 = flags[0];
    const int a_fp32 = a_follows & in_fp32;

    constexpr int TOT4 = K * FOUT / 4;
    if (in_fp32) {
        const float* Wf = (const float*)Wraw;
        for (int i = tid; i < TOT4; i += 256) {
            int idx = i * 4;
            int k = idx / FOUT;
            int n = idx & (FOUT - 1);
            float4 v = *(const float4*)(const void*)(Wf + idx);
            bt[(n + 0) * LDB + k] = f2bf(v.x);
            bt[(n + 1) * LDB + k] = f2bf(v.y);
            bt[(n + 2) * LDB + k] = f2bf(v.z);
            bt[(n + 3) * LDB + k] = f2bf(v.w);
        }
    } else {
        const unsigned short* Ws = (const unsigned short*)Wraw;
        for (int i = tid; i < TOT4; i += 256) {
            int idx = i * 4;
            int k = idx / FOUT;
            int n = idx & (FOUT - 1);
            short4v v = *(const short4v*)(const void*)(Ws + idx);
#pragma unroll
            for (int j = 0; j < 4; j++) bt[(n + j) * LDB + k] = ((const unsigned short*)&v)[j];
        }
    }

    const int wave = tid >> 6;
    const int lane = tid & 63;
    const int quad = lane >> 4;
    const int r16 = lane & 15;

    short8 afrag[2][4];
#pragma unroll
    for (int t = 0; t < 2; t++) {
        int arow = blockIdx.x * 128 + t * 64 + wave * 16 + r16;
        if (arow > Nrows - 1) arow = Nrows - 1;
        if (a_fp32) {
            const float* Ap = (const float*)Araw + (size_t)arow * K + quad * 8;
#pragma unroll
            for (int kk = 0; kk < 4; kk++) {
                float4 f0 = *(const float4*)(const void*)(Ap + kk * 32);
                float4 f1 = *(const float4*)(const void*)(Ap + kk * 32 + 4);
                short8 r;
                r[0] = (short)f2bf(f0.x); r[1] = (short)f2bf(f0.y);
                r[2] = (short)f2bf(f0.z); r[3] = (short)f2bf(f0.w);
                r[4] = (short)f2bf(f1.x); r[5] = (short)f2bf(f1.y);
                r[6] = (short)f2bf(f1.z); r[7] = (short)f2bf(f1.w);
                afrag[t][kk] = r;
            }
        } else {
            const unsigned short* Ap = (const unsigned short*)Araw + (size_t)arow * K + quad * 8;
#pragma unroll
            for (int kk = 0; kk < 4; kk++) afrag[t][kk] = *(const short8*)(const void*)(Ap + kk * 32);
        }
    }

    __syncthreads();

    f32x4 acc[2][NT];
#pragma unroll
    for (int t = 0; t < 2; t++)
#pragma unroll
        for (int nt = 0; nt < NT; nt++) acc[t][nt] = (f32x4){0.f, 0.f, 0.f, 0.f};

#pragma unroll
    for (int kk = 0; kk < 4; kk++) {
#pragma unroll
        for (int nt = 0; nt < NT; nt++) {
            short8 b = *(const short8*)(const void*)(&bt[(nt * 16 + r16) * LDB + kk * 32 + quad * 8]);
#pragma unroll
            for (int t = 0; t < 2; t++)
                acc[t][nt] = __builtin_amdgcn_mfma_f32_16x16x32_bf16(afrag[t][kk], b, acc[t][nt], 0, 0, 0);
        }
    }

    // C layout: col = lane&15, row = quad*4 + r. Pack col pairs via shfl_xor; even lanes store bf16x2.
#pragma unroll
    for (int t = 0; t < 2; t++) {
#pragma unroll
        for (int nt = 0; nt < NT; nt++) {
#pragma unroll
            for (int r = 0; r < 4; r++) {
                float v = acc[t][nt][r];
                float o = __shfl_xor(v, 1, 64);
                int row = blockIdx.x * 128 + t * 64 + wave * 16 + quad * 4 + r;
                if (((lane & 1) == 0) && row < Nrows) {
                    __hip_bfloat162 pk;
                    pk.x = __float2bfloat16(v);
                    pk.y = __float2bfloat16(o);
                    *(__hip_bfloat162*)(out + (size_t)row * FOUT + nt * 16 + r16) = pk;
                }
            }
        }
    }
}

// ---------------- SpMM: wave per node, 8-edge unroll for MLP ----------------

__global__ __launch_bounds__(256) void spmm128_kernel(const int2* __restrict__ edgedat,
                                                      const int* __restrict__ rowptr,
                                                      const int* __restrict__ counts,
                                                      const __hip_bfloat162* __restrict__ Hin,
                                                      __hip_bfloat162* __restrict__ Hout, int N) {
    int wid = (blockIdx.x * 256 + threadIdx.x) >> 6;
    if (wid >= N) return;
    int lane = threadIdx.x & 63;
    int n = __builtin_amdgcn_readfirstlane(wid);
    int start = __builtin_amdgcn_readfirstlane(rowptr[n]);
    int len = __builtin_amdgcn_readfirstlane(counts[n]);
    float ax = 0.f, ay = 0.f;
    int j = 0;
    for (; j + 8 <= len; j += 8) {
        int2 ed[8];
        __hip_bfloat162 hv[8];
#pragma unroll
        for (int u = 0; u < 8; u++) ed[u] = edgedat[start + j + u];
#pragma unroll
        for (int u = 0; u < 8; u++) hv[u] = Hin[(size_t)ed[u].x * 64 + lane];
#pragma unroll
        for (int u = 0; u < 8; u++) {
            float w = __int_as_float(ed[u].y);
            ax += w * __bfloat162float(hv[u].x);
            ay += w * __bfloat162float(hv[u].y);
        }
    }
    for (; j + 4 <= len; j += 4) {
        int2 ed[4];
        __hip_bfloat162 hv[4];
#pragma unroll
        for (int u = 0; u < 4; u++) ed[u] = edgedat[start + j + u];
#pragma unroll
        for (int u = 0; u < 4; u++) hv[u] = Hin[(size_t)ed[u].x * 64 + lane];
#pragma unroll
        for (int u = 0; u < 4; u++) {
            float w = __int_as_float(ed[u].y);
            ax += w * __bfloat162float(hv[u].x);
            ay += w * __bfloat162float(hv[u].y);
        }
    }
    for (; j < len; j++) {
        int2 ed = edgedat[start + j];
        float wt = __int_as_float(ed.y);
        __hip_bfloat162 hv = Hin[(size_t)ed.x * 64 + lane];
        ax += wt * __bfloat162float(hv.x);
        ay += wt * __bfloat162float(hv.y);
    }
    __hip_bfloat162 pk;
    pk.x = __float2bfloat16(fmaxf(ax, 0.f));
    pk.y = __float2bfloat16(fmaxf(ay, 0.f));
    Hout[(size_t)n * 64 + lane] = pk;
}

__global__ __launch_bounds__(256) void spmm64_softmax_kernel(const int2* __restrict__ edgedat,
                                                             const int* __restrict__ rowptr,
                                                             const int* __restrict__ counts,
                                                             const __hip_bfloat16* __restrict__ Hin,
                                                             const int* __restrict__ flags,
                                                             void* __restrict__ Out, int N) {
    int wid = (blockIdx.x * 256 + threadIdx.x) >> 6;
    if (wid >= N) return;
    int lane = threadIdx.x & 63;
    int n = __builtin_amdgcn_readfirstlane(wid);
    int start = __builtin_amdgcn_readfirstlane(rowptr[n]);
    int len = __builtin_amdgcn_readfirstlane(counts[n]);
    float a = 0.f;
    int j = 0;
    for (; j + 8 <= len; j += 8) {
        int2 ed[8];
        float hv[8];
#pragma unroll
        for (int u = 0; u < 8; u++) ed[u] = edgedat[start + j + u];
#pragma unroll
        for (int u = 0; u < 8; u++) hv[u] = __bfloat162float(Hin[(size_t)ed[u].x * 64 + lane]);
#pragma unroll
        for (int u = 0; u < 8; u++) a += __int_as_float(ed[u].y) * hv[u];
    }
    for (; j + 4 <= len; j += 4) {
        int2 ed[4];
        float hv[4];
#pragma unroll
        for (int u = 0; u < 4; u++) ed[u] = edgedat[start + j + u];
#pragma unroll
        for (int u = 0; u < 4; u++) hv[u] = __bfloat162float(Hin[(size_t)ed[u].x * 64 + lane]);
#pragma unroll
        for (int u = 0; u < 4; u++) a += __int_as_float(ed[u].y) * hv[u];
    }
    for (; j < len; j++) {
        int2 ed = edgedat[start + j];
        a += __int_as_float(ed.y) * __bfloat162float(Hin[(size_t)ed.x * 64 + lane]);
    }
    a = fmaxf(a, 0.f);   // relu
    float m = a;
#pragma unroll
    for (int off = 32; off > 0; off >>= 1) m = fmaxf(m, __shfl_xor(m, off, 64));
    float e = __expf(a - m);
    float s = e;
#pragma unroll
    for (int off = 32; off > 0; off >>= 1) s += __shfl_xor(s, off, 64);
    float r = e / s;
    if (flags[0]) {
        ((float*)Out)[(size_t)n * 64 + lane] = r;
    } else {
        ((unsigned short*)Out)[(size_t)n * 64 + lane] = f2bf(r);
    }
}

// ---------------- launch ----------------

extern "C" void kernel_launch(void* const* d_in, const int* in_sizes, int n_in,
                              void* d_out, int out_size, void* d_ws, size_t ws_size,
                              hipStream_t stream) {
    const void* X  = d_in[0];                       // [N,128] bf16 or fp32
    const int*  ei = (const int*)d_in[1];           // [2,E] int32 or int64
    const void* W1 = d_in[2];                       // [128,128]
    const void* W2 = d_in[3];                       // [128,128]
    const void* W3 = d_in[4];                       // [128,64]

    const int N = in_sizes[0] / 128;   // 50000
    const int E = in_sizes[1] / 2;     // 800000

    char* ws = (char*)d_ws;
    size_t off = 0;
    int* counts = (int*)(ws + off);   off += ws_align((size_t)N * 4);
    int* total  = (int*)(ws + off);   off += ws_align(64);
    const size_t zero_bytes = off;    // counts + total need zeroing
    int* flags    = (int*)(ws + off);   off += ws_align(64);
    int* rowptr   = (int*)(ws + off);   off += ws_align((size_t)N * 4);
    float* dinv   = (float*)(ws + off); off += ws_align((size_t)N * 4);
    int* loff     = (int*)(ws + off);   off += ws_align((size_t)E * 4);
    int2* edgedat = (int2*)(ws + off);  off += ws_align((size_t)E * 8);
    unsigned short* HA = (unsigned short*)(ws + off); off += ws_align((size_t)N * 128 * 2);
    unsigned short* HB = (unsigned short*)(ws + off); off += ws_align((size_t)N * 128 * 2);

    hipMemsetAsync(d_ws, 0, zero_bytes, stream);

    sniff_kernel<<<1, 64, 0, stream>>>((const unsigned short*)W1, (const unsigned int*)ei, flags);
    hist_kernel<<<(E + 255) / 256, 256, 0, stream>>>(ei, flags, counts, loff, E);
    alloc_kernel<<<(N + 255) / 256, 256, 0, stream>>>(counts, dinv, rowptr, total, N);
    fill_kernel<<<(E + 255) / 256, 256, 0, stream>>>(ei, flags, dinv, rowptr, loff, edgedat, E);

    const int gblocks = (N + 127) / 128;
    const int sblocks = (N * 64 + 255) / 256;

    // layer 1: HA = X @ W1 ; HB = relu(A_norm HA)
    gemm_kernel<128><<<gblocks, 256, 0, stream>>>(X, 1, W1, flags, HA, N);
    spmm128_kernel<<<sblocks, 256, 0, stream>>>(edgedat, rowptr, counts,
                                                (const __hip_bfloat162*)HA, (__hip_bfloat162*)HB, N);
    // layer 2
    gemm_kernel<128><<<gblocks, 256, 0, stream>>>(HB, 0, W2, flags, HA, N);
    spmm128_kernel<<<sblocks, 256, 0, stream>>>(edgedat, rowptr, counts,
                                                (const __hip_bfloat162*)HA, (__hip_bfloat162*)HB, N);
    // layer 3 (F_out = 64) + relu + softmax
    gemm_kernel<64><<<gblocks, 256, 0, stream>>>(HB, 0, W3, flags, HA, N);
    spmm64_softmax_kernel<<<sblocks, 256, 0, stream>>>(edgedat, rowptr, counts,
                                                       (const __hip_bfloat16*)HA, flags, d_out, N);
}